// Round 7
// baseline (495.935 us; speedup 1.0000x reference)
//
#include <hip/hip_runtime.h>
#include <math.h>

#define BSZ 2
#define SEQ 2048
#define DIM 1024
#define NH 16
#define HDIM 64
#define MR (BSZ*SEQ)   // 4096 rows

typedef __attribute__((ext_vector_type(8))) short bf16x8;
typedef __attribute__((ext_vector_type(4))) short bf16x4;
typedef __attribute__((ext_vector_type(4))) float floatx4;

static __device__ __forceinline__ unsigned short f2bf(float x) {
    unsigned u = __float_as_uint(x);
    u += 0x7fffu + ((u >> 16) & 1u);
    return (unsigned short)(u >> 16);
}
static __device__ __forceinline__ float bf2f(unsigned short h) {
    return __uint_as_float(((unsigned)h) << 16);
}
#define MFMA16(a,b,c) __builtin_amdgcn_mfma_f32_16x16x32_bf16((a),(b),(c),0,0,0)

// 16x16x16 bf16 MFMA (K=16): A,B = 4 bf16/lane at k=quad*4+j.
static __device__ __forceinline__ floatx4 pv_mfma(bf16x4 a, bf16x4 b, floatx4 c) {
#if __has_builtin(__builtin_amdgcn_mfma_f32_16x16x16bf16_1k)
    return __builtin_amdgcn_mfma_f32_16x16x16bf16_1k(a, b, c, 0, 0, 0);
#else
    bf16x8 a8 = {a[0],a[1],a[2],a[3],0,0,0,0};
    bf16x8 b8 = {b[0],b[1],b[2],b[3],0,0,0,0};
    return MFMA16(a8, b8, c);
#endif
}

// async global->LDS, 16B per lane; LDS dest = wave-uniform base + lane*16
static __device__ __forceinline__ void gll16(const unsigned short* g, unsigned short* l) {
    __builtin_amdgcn_global_load_lds(
        (const __attribute__((address_space(1))) void*)g,
        (__attribute__((address_space(3))) void*)l,
        16, 0, 0);
}

// ---------------------------------------------------------------------------
// conv_split: fp32 [rows][1024] -> bf16 [rows][2048] as [hi | lo]
// ---------------------------------------------------------------------------
__global__ __launch_bounds__(256)
void conv_split(const float* p0, const float* p1, const float* p2,
                const float* p3,
                unsigned short* o0, unsigned short* o1, unsigned short* o2,
                unsigned short* o3,
                int r0, int r1, int r2, int r3)
{
    const float* pin; unsigned short* pout; int rows;
    switch (blockIdx.y) {
        case 0: pin=p0; pout=o0; rows=r0; break;
        case 1: pin=p1; pout=o1; rows=r1; break;
        case 2: pin=p2; pout=o2; rows=r2; break;
        default: pin=p3; pout=o3; rows=r3; break;
    }
    size_t idx = (size_t)blockIdx.x * 256 + threadIdx.x;   // group of 4 floats
    if (idx * 4 >= (size_t)rows * DIM) return;
    size_t row = (idx * 4) >> 10;
    int col = (int)((idx * 4) & 1023);
    float4 f = *(const float4*)(pin + idx * 4);
    ushort4 h, l;
    h.x = f2bf(f.x); l.x = f2bf(f.x - bf2f(h.x));
    h.y = f2bf(f.y); l.y = f2bf(f.y - bf2f(h.y));
    h.z = f2bf(f.z); l.z = f2bf(f.z - bf2f(h.z));
    h.w = f2bf(f.w); l.w = f2bf(f.w - bf2f(h.w));
    *(ushort4*)(pout + row * 2048 + col)        = h;
    *(ushort4*)(pout + row * 2048 + 1024 + col) = l;
}

// conv_hi: fp32 flat -> bf16 flat (hi only), 3 matrices via blockIdx.y
__global__ __launch_bounds__(256)
void conv_hi(const float* p0, const float* p1, const float* p2,
             unsigned short* o0, unsigned short* o1, unsigned short* o2,
             int n0, int n1, int n2)
{
    const float* pin; unsigned short* pout; int n;
    switch (blockIdx.y) {
        case 0: pin=p0; pout=o0; n=n0; break;
        case 1: pin=p1; pout=o1; n=n1; break;
        default: pin=p2; pout=o2; n=n2; break;
    }
    size_t idx = (size_t)blockIdx.x * 256 + threadIdx.x;
    if (idx * 4 >= (size_t)n) return;
    float4 f = *(const float4*)(pin + idx * 4);
    ushort4 h;
    h.x = f2bf(f.x); h.y = f2bf(f.y); h.z = f2bf(f.z); h.w = f2bf(f.w);
    *(ushort4*)(pout + idx * 4) = h;
}

// ---------------------------------------------------------------------------
// bf16 MFMA GEMM, m97-style: global_load_lds width-16 staging into unpadded
// 128x64 LDS tiles with XOR chunk swizzle (chunk ^ (row&7)); 2-barrier K-loop.
// ---------------------------------------------------------------------------
template<int EPI, bool SPLIT3>
__global__ __launch_bounds__(256)
void gemm_mfma(const unsigned short* __restrict__ A0, const unsigned short* __restrict__ A1,
               const unsigned short* __restrict__ B0, const unsigned short* __restrict__ B1,
               void* C0v, void* C1v, int lda, int ldb, int nkb)
{
    const unsigned short* A = blockIdx.z ? A1 : A0;
    const unsigned short* B = blockIdx.z ? B1 : B0;
    float* Cf = (float*)(blockIdx.z ? C1v : C0v);
    unsigned short* Cb = (unsigned short*)(blockIdx.z ? C1v : C0v);

    __shared__ __align__(16) unsigned short As[128*64];
    __shared__ __align__(16) unsigned short Bs[128*64];

    const int tid = threadIdx.x;
    const int lane = tid & 63, wv = tid >> 6;
    const int c = lane & 15, quad = lane >> 4;
    const int wm = wv >> 1, wn = wv & 1;
    const int rowBase = blockIdx.y << 7;
    const int colBase = blockIdx.x << 7;

    // staging geometry: each wave stages rows [wv*32, wv*32+32) of both tiles,
    // 4 instrs x (8 rows x 128B); lane -> (srow = lane>>3, lds chunk = lane&7),
    // global chunk = (lane&7) ^ (row&7) = (lane&7) ^ srow  (rows are 8-aligned)
    const int srow = lane >> 3;
    const int schunk = (lane & 7) ^ srow;
    const int segRow = wv * 32;
    const unsigned short* Agb = A + (size_t)(rowBase + segRow + srow) * lda + schunk*8;
    const unsigned short* Bgb = B + (size_t)(colBase + segRow + srow) * ldb + schunk*8;
    unsigned short* Alb = &As[segRow * 64];
    unsigned short* Blb = &Bs[segRow * 64];

    floatx4 acc[4][4];
#pragma unroll
    for (int i = 0; i < 4; ++i)
#pragma unroll
        for (int j = 0; j < 4; ++j) acc[i][j] = (floatx4){0.f,0.f,0.f,0.f};

    for (int kb = 0; kb < nkb; ++kb) {
        int aoff, boff;
        if (SPLIT3) {
            int t = kb >> 4, kk2 = (kb & 15) << 6;
            aoff = ((t == 1) ? 1024 : 0) + kk2;
            boff = ((t == 2) ? 1024 : 0) + kk2;
        } else { aoff = boff = kb << 6; }
        __syncthreads();   // previous tile's frag reads complete
#pragma unroll
        for (int i = 0; i < 4; ++i) {
            gll16(Agb + aoff + (size_t)(i*8)*lda, Alb + i*512);
            gll16(Bgb + boff + (size_t)(i*8)*ldb, Blb + i*512);
        }
        __syncthreads();   // drains vmcnt(0): tiles visible
#pragma unroll
        for (int ks = 0; ks < 2; ++ks) {
            const int ch = ((ks << 2) + quad) ^ (c & 7);
            bf16x8 af[4], bfr[4];
#pragma unroll
            for (int i = 0; i < 4; ++i) {
                af[i]  = *(const bf16x8*)&As[(wm*64 + i*16 + c)*64 + ch*8];
                bfr[i] = *(const bf16x8*)&Bs[(wn*64 + i*16 + c)*64 + ch*8];
            }
#pragma unroll
            for (int mi = 0; mi < 4; ++mi)
#pragma unroll
                for (int ni = 0; ni < 4; ++ni)
                    acc[mi][ni] = MFMA16(af[mi], bfr[ni], acc[mi][ni]);
        }
    }
    const int row0 = rowBase + wm*64 + quad*4;
    if (EPI == 0) {
        const int col0 = colBase + wn*64 + c;
#pragma unroll
        for (int mi = 0; mi < 4; ++mi)
#pragma unroll
            for (int r = 0; r < 4; ++r) {
                size_t ro = (size_t)(row0 + mi*16 + r) * 1024 + col0;
#pragma unroll
                for (int ni = 0; ni < 4; ++ni)
                    Cf[ro + ni*16] = acc[mi][ni][r];
            }
    } else if (EPI == 1) {
        const int h = (colBase >> 6) + wn;       // head index
#pragma unroll
        for (int mi = 0; mi < 4; ++mi)
#pragma unroll
            for (int r = 0; r < 4; ++r) {
                int row = row0 + mi*16 + r;
                int b = row >> 11, s = row & 2047;
                size_t base = ((size_t)((b<<4) | h) * 2048 + s) * 128;
#pragma unroll
                for (int ni = 0; ni < 4; ++ni) {
                    int d = ni*16 + c;
                    float x = acc[mi][ni][r];
                    unsigned short hb = f2bf(x);
                    Cb[base + d]      = hb;
                    Cb[base + 64 + d] = f2bf(x - bf2f(hb));
                }
            }
    } else {  // EPI == 2: Vt[bh][d][s]
        const int h = (colBase >> 6) + wn;
#pragma unroll
        for (int mi = 0; mi < 4; ++mi) {
            int row = row0 + mi*16;
            int b = row >> 11, s = row & 2047;
#pragma unroll
            for (int ni = 0; ni < 4; ++ni) {
                int d = ni*16 + c;
                size_t base = ((size_t)((b<<4)|h) * 64 + d) * 2048 + s;
                ushort4 o4;
                o4.x = f2bf(acc[mi][ni][0]); o4.y = f2bf(acc[mi][ni][1]);
                o4.z = f2bf(acc[mi][ni][2]); o4.w = f2bf(acc[mi][ni][3]);
                *(ushort4*)(Cb + base) = o4;
            }
        }
    }
}

// ---------------------------------------------------------------------------
// def_w: Q-tile 128, 4 waves x M=32, K-tile register prefetch (unchanged).
// Writes def_w * 0.125.
// ---------------------------------------------------------------------------
__global__ __launch_bounds__(256)
void defw_mfma(const unsigned short* __restrict__ qd,
               const unsigned short* __restrict__ kd,
               float* __restrict__ defw)
{
    __shared__ __align__(16) unsigned short Ks[64][136];
    const int tid = threadIdx.x;
    const int wv = tid >> 6, lane = tid & 63;
    const int c = lane & 15, quad = lane >> 4;
    const int bh = blockIdx.y;
    const int qbase = blockIdx.x << 7;
    const int trow = tid >> 2, seg = tid & 3;

    bf16x8 qhi[2][2], qlo[2][2];
#pragma unroll
    for (int mi = 0; mi < 2; ++mi) {
        const unsigned short* qrow =
            qd + ((size_t)bh*2048 + qbase + wv*32 + mi*16 + c)*128 + quad*8;
        qhi[mi][0] = *(const bf16x8*)(qrow);
        qhi[mi][1] = *(const bf16x8*)(qrow + 32);
        qlo[mi][0] = *(const bf16x8*)(qrow + 64);
        qlo[mi][1] = *(const bf16x8*)(qrow + 96);
    }
    float rs[2][4] = {{0.f,0.f,0.f,0.f},{0.f,0.f,0.f,0.f}};
    const unsigned short* kbase = kd + (size_t)bh*2048*128;
    bf16x8 kpre[4];
    {
        const unsigned short* kp = kbase + (size_t)trow*128 + seg*32;
#pragma unroll
        for (int u = 0; u < 4; ++u) kpre[u] = *(const bf16x8*)(kp + 8*u);
    }
    for (int kt = 0; kt < SEQ; kt += 64) {
        __syncthreads();
#pragma unroll
        for (int u = 0; u < 4; ++u) *(bf16x8*)&Ks[trow][seg*32 + 8*u] = kpre[u];
        __syncthreads();
        if (kt + 64 < SEQ) {
            const unsigned short* kp = kbase + (size_t)(kt + 64 + trow)*128 + seg*32;
#pragma unroll
            for (int u = 0; u < 4; ++u) kpre[u] = *(const bf16x8*)(kp + 8*u);
        }
#pragma unroll
        for (int nk = 0; nk < 4; ++nk) {
            const unsigned short* kr = &Ks[16*nk + c][quad*8];
            bf16x8 kh0 = *(const bf16x8*)(kr);
            bf16x8 kh1 = *(const bf16x8*)(kr + 32);
            bf16x8 kl0 = *(const bf16x8*)(kr + 64);
            bf16x8 kl1 = *(const bf16x8*)(kr + 96);
#pragma unroll
            for (int mi = 0; mi < 2; ++mi) {
                floatx4 s = {0.f,0.f,0.f,0.f};
                s = MFMA16(qhi[mi][0], kh0, s);
                s = MFMA16(qhi[mi][1], kh1, s);
                s = MFMA16(qlo[mi][0], kh0, s);
                s = MFMA16(qlo[mi][1], kh1, s);
                s = MFMA16(qhi[mi][0], kl0, s);
                s = MFMA16(qhi[mi][1], kl1, s);
#pragma unroll
                for (int r = 0; r < 4; ++r)
                    rs[mi][r] += 1.f / (1.f + __expf(-0.125f * s[r]));
            }
        }
    }
#pragma unroll
    for (int mi = 0; mi < 2; ++mi)
#pragma unroll
        for (int r = 0; r < 4; ++r) {
            float vv = rs[mi][r];
            vv += __shfl_xor(vv, 1, 16);
            vv += __shfl_xor(vv, 2, 16);
            vv += __shfl_xor(vv, 4, 16);
            vv += __shfl_xor(vv, 8, 16);
            if (c == 0)
                defw[(size_t)bh*SEQ + qbase + wv*32 + mi*16 + 4*quad + r]
                    = vv * 0.125f;   // pre-fold the 1/sqrt(HD) scale
        }
}

// ---------------------------------------------------------------------------
// Flash attention, transposed-score formulation (unchanged from round 6).
// ---------------------------------------------------------------------------
__global__ __launch_bounds__(256)
void flash_mfma(const unsigned short* __restrict__ q,
                const unsigned short* __restrict__ kk,
                const unsigned short* __restrict__ vt,
                const float* __restrict__ dwg,
                unsigned short* __restrict__ o)
{
    __shared__ __align__(16) unsigned short Ks[64][136];
    __shared__ __align__(16) unsigned short Vs[64][72];
    const int tid = threadIdx.x;
    const int wv = tid >> 6, lane = tid & 63;
    const int c = lane & 15, quad = lane >> 4;
    const int bh = blockIdx.y, b = bh >> 4, h = bh & 15;
    const int qbase = blockIdx.x << 7;
    const int trow = tid >> 2, seg = tid & 3;

    bf16x8 qhi[2][2], qlo[2][2];
#pragma unroll
    for (int mi = 0; mi < 2; ++mi) {
        const unsigned short* qrow =
            q + ((size_t)bh*2048 + qbase + wv*32 + mi*16 + c)*128 + quad*8;
        qhi[mi][0] = *(const bf16x8*)(qrow);
        qhi[mi][1] = *(const bf16x8*)(qrow + 32);
        qlo[mi][0] = *(const bf16x8*)(qrow + 64);
        qlo[mi][1] = *(const bf16x8*)(qrow + 96);
    }
    floatx4 Oa[4][2];    // [nd][mi], O^T[d][s]
#pragma unroll
    for (int nd = 0; nd < 4; ++nd)
#pragma unroll
        for (int mi = 0; mi < 2; ++mi) Oa[nd][mi] = (floatx4){0.f,0.f,0.f,0.f};
    float mrun[2] = {-3.0e38f, -3.0e38f}, lrun[2] = {0.f, 0.f};

    const unsigned short* kbase = kk + (size_t)bh*2048*128;
    const unsigned short* vbase = vt + (size_t)bh*64*2048;

    bf16x8 kpre[4], vpre[2];
    {
        const unsigned short* kp = kbase + (size_t)trow*128 + seg*32;
#pragma unroll
        for (int u = 0; u < 4; ++u) kpre[u] = *(const bf16x8*)(kp + 8*u);
        const unsigned short* vp = vbase + (size_t)trow*2048 + seg*16;
        vpre[0] = *(const bf16x8*)(vp);
        vpre[1] = *(const bf16x8*)(vp + 8);
    }

    for (int kt = 0; kt < SEQ; kt += 64) {
        __syncthreads();   // prev tile frag reads done
#pragma unroll
        for (int u = 0; u < 4; ++u) *(bf16x8*)&Ks[trow][seg*32 + 8*u] = kpre[u];
        *(bf16x8*)&Vs[trow][seg*16 + 0] = vpre[0];
        *(bf16x8*)&Vs[trow][seg*16 + 8] = vpre[1];
        float dwf[4][4];
#pragma unroll
        for (int nk = 0; nk < 4; ++nk) {
            float4 d4 = *(const float4*)&dwg[(size_t)bh*SEQ + kt + nk*16 + quad*4];
            dwf[nk][0]=d4.x; dwf[nk][1]=d4.y; dwf[nk][2]=d4.z; dwf[nk][3]=d4.w;
        }
        __syncthreads();   // K,V tiles visible
        if (kt + 64 < SEQ) {   // prefetch next tile during compute
            const unsigned short* kp = kbase + (size_t)(kt + 64 + trow)*128 + seg*32;
#pragma unroll
            for (int u = 0; u < 4; ++u) kpre[u] = *(const bf16x8*)(kp + 8*u);
            const unsigned short* vp = vbase + (size_t)trow*2048 + (kt + 64) + seg*16;
            vpre[0] = *(const bf16x8*)(vp);
            vpre[1] = *(const bf16x8*)(vp + 8);
        }

        float z[2][4][4];   // [mi][nk][r]: t=nk*16+quad*4+r, s=mi*16+c
#pragma unroll
        for (int nk = 0; nk < 4; ++nk) {
            const unsigned short* kr = &Ks[16*nk + c][quad*8];
            bf16x8 kh0 = *(const bf16x8*)(kr);
            bf16x8 kh1 = *(const bf16x8*)(kr + 32);
            bf16x8 kl0 = *(const bf16x8*)(kr + 64);
            bf16x8 kl1 = *(const bf16x8*)(kr + 96);
#pragma unroll
            for (int mi = 0; mi < 2; ++mi) {
                floatx4 s = {0.f,0.f,0.f,0.f};
                s = MFMA16(kh0, qhi[mi][0], s);
                s = MFMA16(kh1, qhi[mi][1], s);
                s = MFMA16(kh0, qlo[mi][0], s);
                s = MFMA16(kh1, qlo[mi][1], s);
                s = MFMA16(kl0, qhi[mi][0], s);
                s = MFMA16(kl1, qhi[mi][1], s);
#pragma unroll
                for (int r = 0; r < 4; ++r) z[mi][nk][r] = s[r] * dwf[nk][r];
            }
        }
        float alpha[2];
#pragma unroll
        for (int mi = 0; mi < 2; ++mi) {
            float tm = z[mi][0][0];
#pragma unroll
            for (int nk = 0; nk < 4; ++nk)
#pragma unroll
                for (int r = 0; r < 4; ++r) tm = fmaxf(tm, z[mi][nk][r]);
            tm = fmaxf(tm, __shfl_xor(tm, 16));
            tm = fmaxf(tm, __shfl_xor(tm, 32));
            float mn = fmaxf(mrun[mi], tm);
            alpha[mi] = __expf(mrun[mi] - mn);
            mrun[mi] = mn;
            float rsum = 0.f;
#pragma unroll
            for (int nk = 0; nk < 4; ++nk)
#pragma unroll
                for (int r = 0; r < 4; ++r) {
                    z[mi][nk][r] = __expf(z[mi][nk][r] - mn);
                    rsum += z[mi][nk][r];
                }
            rsum += __shfl_xor(rsum, 16);
            rsum += __shfl_xor(rsum, 32);
            lrun[mi] = lrun[mi] * alpha[mi] + rsum;
        }
        bf16x4 pb[2][4];
#pragma unroll
        for (int mi = 0; mi < 2; ++mi)
#pragma unroll
            for (int nk = 0; nk < 4; ++nk) {
                bf16x4 p;
                p[0] = (short)f2bf(z[mi][nk][0]);
                p[1] = (short)f2bf(z[mi][nk][1]);
                p[2] = (short)f2bf(z[mi][nk][2]);
                p[3] = (short)f2bf(z[mi][nk][3]);
                pb[mi][nk] = p;
            }
#pragma unroll
        for (int nd = 0; nd < 4; ++nd)
#pragma unroll
            for (int mi = 0; mi < 2; ++mi)
#pragma unroll
                for (int r = 0; r < 4; ++r)
                    Oa[nd][mi][r] *= alpha[mi];
#pragma unroll
        for (int ks = 0; ks < 4; ++ks)
#pragma unroll
            for (int nd = 0; nd < 4; ++nd) {
                bf16x4 va = *(const bf16x4*)&Vs[nd*16 + c][ks*16 + quad*4];
#pragma unroll
                for (int mi = 0; mi < 2; ++mi)
                    Oa[nd][mi] = pv_mfma(va, pb[mi][ks], Oa[nd][mi]);
            }
    }
#pragma unroll
    for (int mi = 0; mi < 2; ++mi) {
        float invl = 1.f / lrun[mi];
        int s_abs = qbase + wv*32 + mi*16 + c;
        unsigned short* orow = o + ((size_t)(b*SEQ + s_abs))*DIM + h*HDIM;
#pragma unroll
        for (int nd = 0; nd < 4; ++nd) {
            ushort4 o4;
            o4.x = f2bf(Oa[nd][mi][0] * invl);
            o4.y = f2bf(Oa[nd][mi][1] * invl);
            o4.z = f2bf(Oa[nd][mi][2] * invl);
            o4.w = f2bf(Oa[nd][mi][3] * invl);
            *(ushort4*)(orow + nd*16 + quad*4) = o4;
        }
    }
}

// ---------------------------------------------------------------------------
extern "C" void kernel_launch(void* const* d_in, const int* in_sizes, int n_in,
                              void* d_out, int out_size, void* d_ws, size_t ws_size,
                              hipStream_t stream)
{
    (void)in_sizes; (void)n_in; (void)out_size; (void)ws_size;
    const float* qi     = (const float*)d_in[0];
    const float* ki     = (const float*)d_in[1];
    const float* vi     = (const float*)d_in[2];
    const float* Wq     = (const float*)d_in[3];
    const float* Wq_def = (const float*)d_in[4];
    const float* Wk     = (const float*)d_in[5];
    const float* Wk_def = (const float*)d_in[6];
    const float* Wv     = (const float*)d_in[7];
    const float* Wo     = (const float*)d_in[8];
    float* out = (float*)d_out;

    char* ws = (char*)d_ws;
    const size_t MB = 1024 * 1024;
    // phase 1 (projections):
    unsigned short* Aq  = (unsigned short*)(ws +  0*MB);  // [4096][2048] hi|lo, 16 MB
    unsigned short* Ak  = (unsigned short*)(ws + 16*MB);  // 16 MB
    unsigned short* Bx  = (unsigned short*)(ws + 32*MB);  // 4 MB  (Bqd then Bq)
    unsigned short* By  = (unsigned short*)(ws + 36*MB);  // 4 MB  (Bkd then Bk)
    unsigned short* qs  = (unsigned short*)(ws + 40*MB);  // [32bh][2048][128] = 16 MB
    unsigned short* ks  = (unsigned short*)(ws + 56*MB);  // 16 MB
    float*          dw  = (float*)(ws + 72*MB);           // 256 KB
    // phase 2 overlays (Aq/Ak dead):
    unsigned short* Av  = (unsigned short*)(ws +  0*MB);  // 8 MB
    unsigned short* Bv  = (unsigned short*)(ws +  8*MB);  // 2 MB
    unsigned short* Bo  = (unsigned short*)(ws + 10*MB);  // 2 MB
    unsigned short* Vt  = (unsigned short*)(ws + 12*MB);  // [32bh][64][2048] = 8 MB
    unsigned short* att = (unsigned short*)(ws + 20*MB);  // [4096][1024] bf16 = 8 MB

    dim3 cb(256);
    dim3 gP(DIM/128, MR/128, 2);    // (8, 32, 2)
    dim3 gS(DIM/128, MR/128, 1);
    dim3 gA(SEQ/128, BSZ*NH);       // (16, 32) — Q-tile 128

    // 1. split-convert qi, ki, def weights
    conv_split<<<dim3(4096, 4), cb, 0, stream>>>(
        qi, ki, Wq_def, Wk_def, Aq, Ak, Bx, By, MR, MR, DIM, DIM);
    // 2. q_def, k_def -> split-bh layout
    gemm_mfma<1, true><<<gP, cb, 0, stream>>>(Aq, Ak, Bx, By, qs, ks, 2048, 2048, 48);
    // 3. defeasible weights (pre-scaled by 0.125)
    defw_mfma<<<gA, cb, 0, stream>>>(qs, ks, dw);
    // 4. main weights (overwrite def weights)
    conv_split<<<dim3(1024, 2), cb, 0, stream>>>(
        Wq, Wk, Wq, Wk, Bx, By, Bx, By, DIM, DIM, 0, 0);
    // 5. q, k -> split-bh layout
    gemm_mfma<1, true><<<gP, cb, 0, stream>>>(Aq, Ak, Bx, By, qs, ks, 2048, 2048, 48);
    // 6. hi converts for v path (Aq/Ak dead)
    conv_hi<<<dim3(4096, 3), cb, 0, stream>>>(vi, Wv, Wo, Av, Bv, Bo,
                                              MR*DIM, DIM*DIM, DIM*DIM);
    // 7. v projection -> V^T layout
    gemm_mfma<2, false><<<gS, cb, 0, stream>>>(Av, Av, Bv, Bv, Vt, Vt, 1024, 1024, 16);
    // 8. attention
    flash_mfma<<<gA, cb, 0, stream>>>(qs, ks, Vt, dw, att);
    // 9. output projection
    gemm_mfma<0, false><<<gS, cb, 0, stream>>>(att, att, Bo, Bo, out, out, 1024, 1024, 16);
}

// Round 8
// 442.274 us; speedup vs baseline: 1.1213x; 1.1213x over previous
//
#include <hip/hip_runtime.h>
#include <math.h>

#define BSZ 2
#define SEQ 2048
#define DIM 1024
#define NH 16
#define HDIM 64
#define MR (BSZ*SEQ)   // 4096 rows

typedef __attribute__((ext_vector_type(8))) short bf16x8;
typedef __attribute__((ext_vector_type(4))) short bf16x4;
typedef __attribute__((ext_vector_type(4))) float floatx4;
typedef _Float16 f16x8 __attribute__((ext_vector_type(8)));

static __device__ __forceinline__ unsigned short f2bf(float x) {
    unsigned u = __float_as_uint(x);
    u += 0x7fffu + ((u >> 16) & 1u);
    return (unsigned short)(u >> 16);
}
static __device__ __forceinline__ float bf2f(unsigned short h) {
    return __uint_as_float(((unsigned)h) << 16);
}
static __device__ __forceinline__ unsigned short f2h(float x) {
    union { _Float16 h; unsigned short u; } v;
    v.h = (_Float16)x;
    return v.u;
}
#define MFMA16(a,b,c) __builtin_amdgcn_mfma_f32_16x16x32_bf16((a),(b),(c),0,0,0)

static __device__ __forceinline__ floatx4 mfma_f16(bf16x8 a, bf16x8 b, floatx4 c) {
    union { bf16x8 s; f16x8 h; } ua, ub;
    ua.s = a; ub.s = b;
    return __builtin_amdgcn_mfma_f32_16x16x32_f16(ua.h, ub.h, c, 0, 0, 0);
}

// 16x16x16 bf16 MFMA (K=16): A,B = 4 bf16/lane at k=quad*4+j.
static __device__ __forceinline__ floatx4 pv_mfma(bf16x4 a, bf16x4 b, floatx4 c) {
#if __has_builtin(__builtin_amdgcn_mfma_f32_16x16x16bf16_1k)
    return __builtin_amdgcn_mfma_f32_16x16x16bf16_1k(a, b, c, 0, 0, 0);
#else
    bf16x8 a8 = {a[0],a[1],a[2],a[3],0,0,0,0};
    bf16x8 b8 = {b[0],b[1],b[2],b[3],0,0,0,0};
    return MFMA16(a8, b8, c);
#endif
}

// ---------------------------------------------------------------------------
// conv_split: fp32 [rows][1024] -> bf16 [rows][2048] as [hi | lo]
// ---------------------------------------------------------------------------
__global__ __launch_bounds__(256)
void conv_split(const float* p0, const float* p1, const float* p2,
                const float* p3,
                unsigned short* o0, unsigned short* o1, unsigned short* o2,
                unsigned short* o3,
                int r0, int r1, int r2, int r3)
{
    const float* pin; unsigned short* pout; int rows;
    switch (blockIdx.y) {
        case 0: pin=p0; pout=o0; rows=r0; break;
        case 1: pin=p1; pout=o1; rows=r1; break;
        case 2: pin=p2; pout=o2; rows=r2; break;
        default: pin=p3; pout=o3; rows=r3; break;
    }
    size_t idx = (size_t)blockIdx.x * 256 + threadIdx.x;   // group of 4 floats
    if (idx * 4 >= (size_t)rows * DIM) return;
    size_t row = (idx * 4) >> 10;
    int col = (int)((idx * 4) & 1023);
    float4 f = *(const float4*)(pin + idx * 4);
    ushort4 h, l;
    h.x = f2bf(f.x); l.x = f2bf(f.x - bf2f(h.x));
    h.y = f2bf(f.y); l.y = f2bf(f.y - bf2f(h.y));
    h.z = f2bf(f.z); l.z = f2bf(f.z - bf2f(h.z));
    h.w = f2bf(f.w); l.w = f2bf(f.w - bf2f(h.w));
    *(ushort4*)(pout + row * 2048 + col)        = h;
    *(ushort4*)(pout + row * 2048 + 1024 + col) = l;
}

// conv_f16: fp32 flat -> fp16 flat, 4 matrices via blockIdx.y
__global__ __launch_bounds__(256)
void conv_f16(const float* p0, const float* p1, const float* p2, const float* p3,
              unsigned short* o0, unsigned short* o1, unsigned short* o2,
              unsigned short* o3, int r0, int r1, int r2, int r3)
{
    const float* pin; unsigned short* pout; int rows;
    switch (blockIdx.y) {
        case 0: pin=p0; pout=o0; rows=r0; break;
        case 1: pin=p1; pout=o1; rows=r1; break;
        case 2: pin=p2; pout=o2; rows=r2; break;
        default: pin=p3; pout=o3; rows=r3; break;
    }
    size_t idx = (size_t)blockIdx.x * 256 + threadIdx.x;
    if (idx * 4 >= (size_t)rows * DIM) return;
    float4 f = *(const float4*)(pin + idx * 4);
    ushort4 h;
    h.x = f2h(f.x); h.y = f2h(f.y); h.z = f2h(f.z); h.w = f2h(f.w);
    *(ushort4*)(pout + idx * 4) = h;
}

// conv_hi: fp32 flat -> bf16 flat (hi only), 3 matrices via blockIdx.y
__global__ __launch_bounds__(256)
void conv_hi(const float* p0, const float* p1, const float* p2,
             unsigned short* o0, unsigned short* o1, unsigned short* o2,
             int n0, int n1, int n2)
{
    const float* pin; unsigned short* pout; int n;
    switch (blockIdx.y) {
        case 0: pin=p0; pout=o0; n=n0; break;
        case 1: pin=p1; pout=o1; n=n1; break;
        default: pin=p2; pout=o2; n=n2; break;
    }
    size_t idx = (size_t)blockIdx.x * 256 + threadIdx.x;
    if (idx * 4 >= (size_t)n) return;
    float4 f = *(const float4*)(pin + idx * 4);
    ushort4 h;
    h.x = f2bf(f.x); h.y = f2bf(f.y); h.z = f2bf(f.z); h.w = f2bf(f.w);
    *(ushort4*)(pout + idx * 4) = h;
}

// ---------------------------------------------------------------------------
// MFMA GEMM (round-6 verified body + DT dtype switch).
// DT: 0 = bf16 MFMA, 1 = fp16 MFMA.
// EPI: 0 = fp32 row-major [.][1024]
//      1 = split-bf16 per-(b,h): out[bh][s][0..63 hi | 64..127 lo]
//      2 = V^T per-(b,h):        out[bh][d][s]   (bf16)
//      3 = fp16 per-(b,h):       out[bh][s][d]   (fp16)
// ---------------------------------------------------------------------------
template<int EPI, bool SPLIT3, int DT>
__global__ __launch_bounds__(256)
void gemm_mfma(const unsigned short* __restrict__ A0, const unsigned short* __restrict__ A1,
               const unsigned short* __restrict__ B0, const unsigned short* __restrict__ B1,
               void* C0v, void* C1v, int lda, int ldb, int nkb)
{
    const unsigned short* A = blockIdx.z ? A1 : A0;
    const unsigned short* B = blockIdx.z ? B1 : B0;
    float* Cf = (float*)(blockIdx.z ? C1v : C0v);
    unsigned short* Cb = (unsigned short*)(blockIdx.z ? C1v : C0v);

    __shared__ __align__(16) unsigned short As[128][72];
    __shared__ __align__(16) unsigned short Bs[128][72];

    const int tid = threadIdx.x;
    const int lane = tid & 63, wv = tid >> 6;
    const int c = lane & 15, quad = lane >> 4;
    const int wm = wv >> 1, wn = wv & 1;
    const int rowBase = blockIdx.y << 7;
    const int colBase = blockIdx.x << 7;

    floatx4 acc[4][4];
#pragma unroll
    for (int i = 0; i < 4; ++i)
#pragma unroll
        for (int j = 0; j < 4; ++j) acc[i][j] = (floatx4){0.f,0.f,0.f,0.f};

    bf16x8 ar[4], br[4];
    {
#pragma unroll
        for (int i = 0; i < 4; ++i) {
            int f = tid + (i << 8);
            int r = f >> 3, kbk = (f & 7) << 3;
            ar[i] = *(const bf16x8*)(A + (size_t)(rowBase + r) * lda + kbk);
            br[i] = *(const bf16x8*)(B + (size_t)(colBase + r) * ldb + kbk);
        }
    }
    for (int kb = 0; kb < nkb; ++kb) {
        __syncthreads();
#pragma unroll
        for (int i = 0; i < 4; ++i) {
            int f = tid + (i << 8);
            int r = f >> 3, kbk = (f & 7) << 3;
            *(bf16x8*)&As[r][kbk] = ar[i];
            *(bf16x8*)&Bs[r][kbk] = br[i];
        }
        __syncthreads();
        if (kb + 1 < nkb) {
            int kn = kb + 1, aoff, boff;
            if (SPLIT3) {
                int t = kn >> 4, kk = (kn & 15) << 6;
                aoff = ((t == 1) ? 1024 : 0) + kk;
                boff = ((t == 2) ? 1024 : 0) + kk;
            } else { aoff = boff = kn << 6; }
#pragma unroll
            for (int i = 0; i < 4; ++i) {
                int f = tid + (i << 8);
                int r = f >> 3, kbk = (f & 7) << 3;
                ar[i] = *(const bf16x8*)(A + (size_t)(rowBase + r) * lda + aoff + kbk);
                br[i] = *(const bf16x8*)(B + (size_t)(colBase + r) * ldb + boff + kbk);
            }
        }
#pragma unroll
        for (int ks = 0; ks < 2; ++ks) {
            bf16x8 af[4], bfr[4];
#pragma unroll
            for (int i = 0; i < 4; ++i) {
                af[i]  = *(const bf16x8*)&As[wm*64 + i*16 + c][ks*32 + quad*8];
                bfr[i] = *(const bf16x8*)&Bs[wn*64 + i*16 + c][ks*32 + quad*8];
            }
#pragma unroll
            for (int mi = 0; mi < 4; ++mi)
#pragma unroll
                for (int ni = 0; ni < 4; ++ni) {
                    if (DT == 0) acc[mi][ni] = MFMA16(af[mi], bfr[ni], acc[mi][ni]);
                    else         acc[mi][ni] = mfma_f16(af[mi], bfr[ni], acc[mi][ni]);
                }
        }
    }
    const int row0 = rowBase + wm*64 + quad*4;
    if (EPI == 0) {
        const int col0 = colBase + wn*64 + c;
#pragma unroll
        for (int mi = 0; mi < 4; ++mi)
#pragma unroll
            for (int r = 0; r < 4; ++r) {
                size_t ro = (size_t)(row0 + mi*16 + r) * 1024 + col0;
#pragma unroll
                for (int ni = 0; ni < 4; ++ni)
                    Cf[ro + ni*16] = acc[mi][ni][r];
            }
    } else if (EPI == 1) {
        const int h = (colBase >> 6) + wn;       // head index
#pragma unroll
        for (int mi = 0; mi < 4; ++mi)
#pragma unroll
            for (int r = 0; r < 4; ++r) {
                int row = row0 + mi*16 + r;
                int b = row >> 11, s = row & 2047;
                size_t base = ((size_t)((b<<4) | h) * 2048 + s) * 128;
#pragma unroll
                for (int ni = 0; ni < 4; ++ni) {
                    int d = ni*16 + c;
                    float x = acc[mi][ni][r];
                    unsigned short hb = f2bf(x);
                    Cb[base + d]      = hb;
                    Cb[base + 64 + d] = f2bf(x - bf2f(hb));
                }
            }
    } else if (EPI == 2) {  // Vt[bh][d][s]
        const int h = (colBase >> 6) + wn;
#pragma unroll
        for (int mi = 0; mi < 4; ++mi) {
            int row = row0 + mi*16;
            int b = row >> 11, s = row & 2047;
#pragma unroll
            for (int ni = 0; ni < 4; ++ni) {
                int d = ni*16 + c;
                size_t base = ((size_t)((b<<4)|h) * 64 + d) * 2048 + s;
                ushort4 o4;
                o4.x = f2bf(acc[mi][ni][0]); o4.y = f2bf(acc[mi][ni][1]);
                o4.z = f2bf(acc[mi][ni][2]); o4.w = f2bf(acc[mi][ni][3]);
                *(ushort4*)(Cb + base) = o4;
            }
        }
    } else {  // EPI == 3: fp16 per-bh [bh][s][64]
        const int h = (colBase >> 6) + wn;
#pragma unroll
        for (int mi = 0; mi < 4; ++mi)
#pragma unroll
            for (int r = 0; r < 4; ++r) {
                int row = row0 + mi*16 + r;
                int b = row >> 11, s = row & 2047;
                size_t base = ((size_t)((b<<4) | h) * 2048 + s) * 64;
#pragma unroll
                for (int ni = 0; ni < 4; ++ni)
                    Cb[base + ni*16 + c] = f2h(acc[mi][ni][r]);
            }
    }
}

// ---------------------------------------------------------------------------
// def_w, fp16: qd/kd are [bh][s][64] fp16. 2 MFMA per nk. Writes def_w*0.125.
// ---------------------------------------------------------------------------
__global__ __launch_bounds__(256)
void defw_mfma(const unsigned short* __restrict__ qd,
               const unsigned short* __restrict__ kd,
               float* __restrict__ defw)
{
    __shared__ __align__(16) unsigned short Ks[64][72];
    const int tid = threadIdx.x;
    const int wv = tid >> 6, lane = tid & 63;
    const int c = lane & 15, quad = lane >> 4;
    const int bh = blockIdx.y;
    const int qbase = blockIdx.x << 7;
    const int trow = tid >> 2, seg = tid & 3;

    bf16x8 qf[2][2];
#pragma unroll
    for (int mi = 0; mi < 2; ++mi) {
        const unsigned short* qrow =
            qd + ((size_t)bh*2048 + qbase + wv*32 + mi*16 + c)*64 + quad*8;
        qf[mi][0] = *(const bf16x8*)(qrow);
        qf[mi][1] = *(const bf16x8*)(qrow + 32);
    }
    float rs[2][4] = {{0.f,0.f,0.f,0.f},{0.f,0.f,0.f,0.f}};
    const unsigned short* kbase = kd + (size_t)bh*2048*64;
    bf16x8 kpre[2];
    {
        const unsigned short* kp = kbase + (size_t)trow*64 + seg*16;
        kpre[0] = *(const bf16x8*)(kp);
        kpre[1] = *(const bf16x8*)(kp + 8);
    }
    for (int kt = 0; kt < SEQ; kt += 64) {
        __syncthreads();
        *(bf16x8*)&Ks[trow][seg*16 + 0] = kpre[0];
        *(bf16x8*)&Ks[trow][seg*16 + 8] = kpre[1];
        __syncthreads();
        if (kt + 64 < SEQ) {
            const unsigned short* kp = kbase + (size_t)(kt + 64 + trow)*64 + seg*16;
            kpre[0] = *(const bf16x8*)(kp);
            kpre[1] = *(const bf16x8*)(kp + 8);
        }
#pragma unroll
        for (int nk = 0; nk < 4; ++nk) {
            const unsigned short* kr = &Ks[16*nk + c][quad*8];
            bf16x8 k0 = *(const bf16x8*)(kr);
            bf16x8 k1 = *(const bf16x8*)(kr + 32);
#pragma unroll
            for (int mi = 0; mi < 2; ++mi) {
                floatx4 s = {0.f,0.f,0.f,0.f};
                s = mfma_f16(qf[mi][0], k0, s);
                s = mfma_f16(qf[mi][1], k1, s);
#pragma unroll
                for (int r = 0; r < 4; ++r)
                    rs[mi][r] += 1.f / (1.f + __expf(-0.125f * s[r]));
            }
        }
    }
#pragma unroll
    for (int mi = 0; mi < 2; ++mi)
#pragma unroll
        for (int r = 0; r < 4; ++r) {
            float vv = rs[mi][r];
            vv += __shfl_xor(vv, 1, 16);
            vv += __shfl_xor(vv, 2, 16);
            vv += __shfl_xor(vv, 4, 16);
            vv += __shfl_xor(vv, 8, 16);
            if (c == 0)
                defw[(size_t)bh*SEQ + qbase + wv*32 + mi*16 + 4*quad + r]
                    = vv * 0.125f;   // pre-fold the 1/sqrt(HD) scale
        }
}

// ---------------------------------------------------------------------------
// Flash attention, transposed-score formulation (unchanged — verified).
// ---------------------------------------------------------------------------
__global__ __launch_bounds__(256)
void flash_mfma(const unsigned short* __restrict__ q,
                const unsigned short* __restrict__ kk,
                const unsigned short* __restrict__ vt,
                const float* __restrict__ dwg,
                unsigned short* __restrict__ o)
{
    __shared__ __align__(16) unsigned short Ks[64][136];
    __shared__ __align__(16) unsigned short Vs[64][72];
    const int tid = threadIdx.x;
    const int wv = tid >> 6, lane = tid & 63;
    const int c = lane & 15, quad = lane >> 4;
    const int bh = blockIdx.y, b = bh >> 4, h = bh & 15;
    const int qbase = blockIdx.x << 7;
    const int trow = tid >> 2, seg = tid & 3;

    bf16x8 qhi[2][2], qlo[2][2];
#pragma unroll
    for (int mi = 0; mi < 2; ++mi) {
        const unsigned short* qrow =
            q + ((size_t)bh*2048 + qbase + wv*32 + mi*16 + c)*128 + quad*8;
        qhi[mi][0] = *(const bf16x8*)(qrow);
        qhi[mi][1] = *(const bf16x8*)(qrow + 32);
        qlo[mi][0] = *(const bf16x8*)(qrow + 64);
        qlo[mi][1] = *(const bf16x8*)(qrow + 96);
    }
    floatx4 Oa[4][2];    // [nd][mi], O^T[d][s]
#pragma unroll
    for (int nd = 0; nd < 4; ++nd)
#pragma unroll
        for (int mi = 0; mi < 2; ++mi) Oa[nd][mi] = (floatx4){0.f,0.f,0.f,0.f};
    float mrun[2] = {-3.0e38f, -3.0e38f}, lrun[2] = {0.f, 0.f};

    const unsigned short* kbase = kk + (size_t)bh*2048*128;
    const unsigned short* vbase = vt + (size_t)bh*64*2048;

    bf16x8 kpre[4], vpre[2];
    {
        const unsigned short* kp = kbase + (size_t)trow*128 + seg*32;
#pragma unroll
        for (int u = 0; u < 4; ++u) kpre[u] = *(const bf16x8*)(kp + 8*u);
        const unsigned short* vp = vbase + (size_t)trow*2048 + seg*16;
        vpre[0] = *(const bf16x8*)(vp);
        vpre[1] = *(const bf16x8*)(vp + 8);
    }

    for (int kt = 0; kt < SEQ; kt += 64) {
        __syncthreads();   // prev tile frag reads done
#pragma unroll
        for (int u = 0; u < 4; ++u) *(bf16x8*)&Ks[trow][seg*32 + 8*u] = kpre[u];
        *(bf16x8*)&Vs[trow][seg*16 + 0] = vpre[0];
        *(bf16x8*)&Vs[trow][seg*16 + 8] = vpre[1];
        float dwf[4][4];
#pragma unroll
        for (int nk = 0; nk < 4; ++nk) {
            float4 d4 = *(const float4*)&dwg[(size_t)bh*SEQ + kt + nk*16 + quad*4];
            dwf[nk][0]=d4.x; dwf[nk][1]=d4.y; dwf[nk][2]=d4.z; dwf[nk][3]=d4.w;
        }
        __syncthreads();   // K,V tiles visible
        if (kt + 64 < SEQ) {   // prefetch next tile during compute
            const unsigned short* kp = kbase + (size_t)(kt + 64 + trow)*128 + seg*32;
#pragma unroll
            for (int u = 0; u < 4; ++u) kpre[u] = *(const bf16x8*)(kp + 8*u);
            const unsigned short* vp = vbase + (size_t)trow*2048 + (kt + 64) + seg*16;
            vpre[0] = *(const bf16x8*)(vp);
            vpre[1] = *(const bf16x8*)(vp + 8);
        }

        float z[2][4][4];   // [mi][nk][r]: t=nk*16+quad*4+r, s=mi*16+c
#pragma unroll
        for (int nk = 0; nk < 4; ++nk) {
            const unsigned short* kr = &Ks[16*nk + c][quad*8];
            bf16x8 kh0 = *(const bf16x8*)(kr);
            bf16x8 kh1 = *(const bf16x8*)(kr + 32);
            bf16x8 kl0 = *(const bf16x8*)(kr + 64);
            bf16x8 kl1 = *(const bf16x8*)(kr + 96);
#pragma unroll
            for (int mi = 0; mi < 2; ++mi) {
                floatx4 s = {0.f,0.f,0.f,0.f};
                s = MFMA16(kh0, qhi[mi][0], s);
                s = MFMA16(kh1, qhi[mi][1], s);
                s = MFMA16(kh0, qlo[mi][0], s);
                s = MFMA16(kh1, qlo[mi][1], s);
                s = MFMA16(kl0, qhi[mi][0], s);
                s = MFMA16(kl1, qhi[mi][1], s);
#pragma unroll
                for (int r = 0; r < 4; ++r) z[mi][nk][r] = s[r] * dwf[nk][r];
            }
        }
        float alpha[2];
#pragma unroll
        for (int mi = 0; mi < 2; ++mi) {
            float tm = z[mi][0][0];
#pragma unroll
            for (int nk = 0; nk < 4; ++nk)
#pragma unroll
                for (int r = 0; r < 4; ++r) tm = fmaxf(tm, z[mi][nk][r]);
            tm = fmaxf(tm, __shfl_xor(tm, 16));
            tm = fmaxf(tm, __shfl_xor(tm, 32));
            float mn = fmaxf(mrun[mi], tm);
            alpha[mi] = __expf(mrun[mi] - mn);
            mrun[mi] = mn;
            float rsum = 0.f;
#pragma unroll
            for (int nk = 0; nk < 4; ++nk)
#pragma unroll
                for (int r = 0; r < 4; ++r) {
                    z[mi][nk][r] = __expf(z[mi][nk][r] - mn);
                    rsum += z[mi][nk][r];
                }
            rsum += __shfl_xor(rsum, 16);
            rsum += __shfl_xor(rsum, 32);
            lrun[mi] = lrun[mi] * alpha[mi] + rsum;
        }
        bf16x4 pb[2][4];
#pragma unroll
        for (int mi = 0; mi < 2; ++mi)
#pragma unroll
            for (int nk = 0; nk < 4; ++nk) {
                bf16x4 p;
                p[0] = (short)f2bf(z[mi][nk][0]);
                p[1] = (short)f2bf(z[mi][nk][1]);
                p[2] = (short)f2bf(z[mi][nk][2]);
                p[3] = (short)f2bf(z[mi][nk][3]);
                pb[mi][nk] = p;
            }
#pragma unroll
        for (int nd = 0; nd < 4; ++nd)
#pragma unroll
            for (int mi = 0; mi < 2; ++mi)
#pragma unroll
                for (int r = 0; r < 4; ++r)
                    Oa[nd][mi][r] *= alpha[mi];
#pragma unroll
        for (int ks = 0; ks < 4; ++ks)
#pragma unroll
            for (int nd = 0; nd < 4; ++nd) {
                bf16x4 va = *(const bf16x4*)&Vs[nd*16 + c][ks*16 + quad*4];
#pragma unroll
                for (int mi = 0; mi < 2; ++mi)
                    Oa[nd][mi] = pv_mfma(va, pb[mi][ks], Oa[nd][mi]);
            }
    }
#pragma unroll
    for (int mi = 0; mi < 2; ++mi) {
        float invl = 1.f / lrun[mi];
        int s_abs = qbase + wv*32 + mi*16 + c;
        unsigned short* orow = o + ((size_t)(b*SEQ + s_abs))*DIM + h*HDIM;
#pragma unroll
        for (int nd = 0; nd < 4; ++nd) {
            ushort4 o4;
            o4.x = f2bf(Oa[nd][mi][0] * invl);
            o4.y = f2bf(Oa[nd][mi][1] * invl);
            o4.z = f2bf(Oa[nd][mi][2] * invl);
            o4.w = f2bf(Oa[nd][mi][3] * invl);
            *(ushort4*)(orow + nd*16 + quad*4) = o4;
        }
    }
}

// ---------------------------------------------------------------------------
extern "C" void kernel_launch(void* const* d_in, const int* in_sizes, int n_in,
                              void* d_out, int out_size, void* d_ws, size_t ws_size,
                              hipStream_t stream)
{
    (void)in_sizes; (void)n_in; (void)out_size; (void)ws_size;
    const float* qi     = (const float*)d_in[0];
    const float* ki     = (const float*)d_in[1];
    const float* vi     = (const float*)d_in[2];
    const float* Wq     = (const float*)d_in[3];
    const float* Wq_def = (const float*)d_in[4];
    const float* Wk     = (const float*)d_in[5];
    const float* Wk_def = (const float*)d_in[6];
    const float* Wv     = (const float*)d_in[7];
    const float* Wo     = (const float*)d_in[8];
    float* out = (float*)d_out;

    char* ws = (char*)d_ws;
    const size_t MB = 1024 * 1024;
    // def phase (fp16):
    unsigned short* Aqf  = (unsigned short*)(ws +  0*MB);  // fp16 qi, 8 MB
    unsigned short* Akf  = (unsigned short*)(ws +  8*MB);  // fp16 ki, 8 MB
    unsigned short* Bqdf = (unsigned short*)(ws + 16*MB);  // fp16 Wq_def, 2 MB
    unsigned short* Bkdf = (unsigned short*)(ws + 18*MB);  // fp16 Wk_def, 2 MB
    unsigned short* qdf  = (unsigned short*)(ws + 20*MB);  // [32bh][2048][64] fp16, 8 MB
    unsigned short* kdf  = (unsigned short*)(ws + 28*MB);  // 8 MB
    // main phase (overwrites def phase after defw):
    unsigned short* Aq  = (unsigned short*)(ws +  0*MB);   // [4096][2048] hi|lo, 16 MB
    unsigned short* Ak  = (unsigned short*)(ws + 16*MB);   // 16 MB
    unsigned short* Bq  = (unsigned short*)(ws + 32*MB);   // 4 MB
    unsigned short* Bk  = (unsigned short*)(ws + 36*MB);   // 4 MB
    unsigned short* qs  = (unsigned short*)(ws + 40*MB);   // [32bh][2048][128], 16 MB
    unsigned short* ks  = (unsigned short*)(ws + 56*MB);   // 16 MB
    float*          dw  = (float*)(ws + 72*MB);            // 256 KB (lives to flash)
    // phase 2 overlays (Aq/Ak/Bq/Bk dead):
    unsigned short* Av  = (unsigned short*)(ws +  0*MB);   // 8 MB
    unsigned short* Bv  = (unsigned short*)(ws +  8*MB);   // 2 MB
    unsigned short* Bo  = (unsigned short*)(ws + 10*MB);   // 2 MB
    unsigned short* Vt  = (unsigned short*)(ws + 12*MB);   // [32bh][64][2048], 8 MB
    unsigned short* att = (unsigned short*)(ws + 20*MB);   // [4096][1024] bf16, 8 MB

    dim3 cb(256);
    dim3 gP(DIM/128, MR/128, 2);    // (8, 32, 2)
    dim3 gS(DIM/128, MR/128, 1);
    dim3 gA(SEQ/128, BSZ*NH);       // (16, 32) — Q-tile 128

    // 1. fp16 converts for the defeasible path
    conv_f16<<<dim3(4096, 4), cb, 0, stream>>>(
        qi, ki, Wq_def, Wk_def, Aqf, Akf, Bqdf, Bkdf, MR, MR, DIM, DIM);
    // 2. q_def, k_def (plain fp16 GEMM) -> [bh][s][64] fp16
    gemm_mfma<3, false, 1><<<gP, cb, 0, stream>>>(Aqf, Akf, Bqdf, Bkdf, qdf, kdf, 1024, 1024, 16);
    // 3. defeasible weights (pre-scaled by 0.125)
    defw_mfma<<<gA, cb, 0, stream>>>(qdf, kdf, dw);
    // 4. split-bf16 converts for the main path (overwrites def buffers)
    conv_split<<<dim3(4096, 4), cb, 0, stream>>>(
        qi, ki, Wq, Wk, Aq, Ak, Bq, Bk, MR, MR, DIM, DIM);
    // 5. q, k (split-3 bf16 GEMM) -> split-bh layout
    gemm_mfma<1, true, 0><<<gP, cb, 0, stream>>>(Aq, Ak, Bq, Bk, qs, ks, 2048, 2048, 48);
    // 6. hi converts for v path (Aq/Ak dead)
    conv_hi<<<dim3(4096, 3), cb, 0, stream>>>(vi, Wv, Wo, Av, Bv, Bo,
                                              MR*DIM, DIM*DIM, DIM*DIM);
    // 7. v projection -> V^T layout
    gemm_mfma<2, false, 0><<<gS, cb, 0, stream>>>(Av, Av, Bv, Bv, Vt, Vt, 1024, 1024, 16);
    // 8. attention
    flash_mfma<<<gA, cb, 0, stream>>>(qs, ks, Vt, dw, att);
    // 9. output projection
    gemm_mfma<0, false, 0><<<gS, cb, 0, stream>>>(att, att, Bo, Bo, out, out, 1024, 1024, 16);
}